// Round 13
// baseline (349.085 us; speedup 1.0000x reference)
//
#include <hip/hip_runtime.h>

#define NNODES 50000
#define NEDGES 800000
#define F 128
#define NREL 8
#define NOUT 1152   // 9*128: 8 relations + self-loop
#define NBKT 98     // ceil(50000 / 512) coarse buckets
#define BSH 9       // 512 nodes per bucket
#define NT64 782    // ceil(50000/64) 64-row tiles
#define CSR_BLOCKS 196

typedef short bf16x8 __attribute__((ext_vector_type(8)));
typedef float f32x4 __attribute__((ext_vector_type(4)));
typedef float f32x2 __attribute__((ext_vector_type(2)));

__device__ __forceinline__ unsigned f2bf(float f) {  // RNE
  unsigned u = __float_as_uint(f);
  u += 0x7fffu + ((u >> 16) & 1u);
  return u >> 16;
}
__device__ __forceinline__ float bf2f(unsigned v) {
  return __uint_as_float(v << 16);
}

// ========== fused prep: chist | cvt | prepw(W1) | prepw(W2) =================
#define PREP_CHIST 196
#define PREP_CVT   12500   // 50000*128/2 / 256
#define PREP_W     576     // 1152*128 / 256
__global__ __launch_bounds__(256)
void k_prep(const int* __restrict__ dst, int* __restrict__ bcnt,
            const float* __restrict__ in_feat, ushort* __restrict__ feat0,
            const float* __restrict__ W1, const float* __restrict__ W1s,
            ushort* __restrict__ Wt1,
            const float* __restrict__ W2, const float* __restrict__ W2s,
            ushort* __restrict__ Wt2) {
  const int b = blockIdx.x, t = threadIdx.x;
  if (b < PREP_CHIST) {
    __shared__ int hist[NBKT];
    if (t < NBKT) hist[t] = 0;
    __syncthreads();
    int e0 = b * 4096;
#pragma unroll
    for (int i = 0; i < 16; ++i) {
      int e = e0 + t + i * 256;
      if (e < NEDGES) atomicAdd(&hist[dst[e] >> BSH], 1);
    }
    __syncthreads();
    if (t < NBKT && hist[t] > 0) atomicAdd(&bcnt[t], hist[t]);
  } else if (b < PREP_CHIST + PREP_CVT) {
    int i = (b - PREP_CHIST) * 256 + t;  // exactly 3.2M
    float2 v = ((const float2*)in_feat)[i];
    ((unsigned*)feat0)[i] = f2bf(v.x) | (f2bf(v.y) << 16);
  } else {
    int w2 = (b >= PREP_CHIST + PREP_CVT + PREP_W);
    int idx = (b - PREP_CHIST - PREP_CVT - (w2 ? PREP_W : 0)) * 256 + t;
    int n = idx >> 7, k = idx & 127;
    int r = n >> 7, c = n & 127;
    const float* Wr = w2 ? W2 : W1;
    const float* Ws = w2 ? W2s : W1s;
    float v = (r < NREL) ? Wr[((size_t)r * F + k) * F + c] : Ws[(size_t)k * F + c];
    (w2 ? Wt2 : Wt1)[idx] = (ushort)f2bf(v);
  }
}

// ================= CSR scan =================================================
__global__ __launch_bounds__(128)
void k_cscan(const int* __restrict__ bcnt, int* __restrict__ bbase,
             int* __restrict__ bcur, int* __restrict__ rowptr) {
  __shared__ int s[128];
  int t = threadIdx.x;
  int v = (t < NBKT) ? bcnt[t] : 0;
  s[t] = v;
  __syncthreads();
  for (int off = 1; off < 128; off <<= 1) {
    int x = (t >= off) ? s[t - off] : 0;
    __syncthreads();
    s[t] += x;
    __syncthreads();
  }
  if (t < NBKT) { bbase[t] = s[t] - v; bcur[t] = s[t] - v; }
  if (t == 0) rowptr[NNODES] = NEDGES;
}

__global__ __launch_bounds__(256)
void k_fsort(const int* __restrict__ ebuf, const int* __restrict__ bbase,
             const int* __restrict__ bcnt, int* __restrict__ rowptr,
             int* __restrict__ edata) {
  __shared__ int cnt[512];
  __shared__ int pos[512];
  __shared__ int ws2[256];
  const int b = blockIdx.x, t = threadIdx.x;
  const int beg = bbase[b], end = beg + bcnt[b];
  cnt[t] = 0; cnt[t + 256] = 0;
  __syncthreads();
  for (int e = beg + t; e < end; e += 256)
    atomicAdd(&cnt[((unsigned)ebuf[e]) >> 19], 1);
  __syncthreads();
  int a = cnt[2 * t], b2 = cnt[2 * t + 1];
  ws2[t] = a + b2;
  __syncthreads();
  for (int off = 1; off < 256; off <<= 1) {
    int x = (t >= off) ? ws2[t - off] : 0;
    __syncthreads();
    ws2[t] += x;
    __syncthreads();
  }
  int ep = ws2[t] - (a + b2);
  pos[2 * t] = ep;
  pos[2 * t + 1] = ep + a;
  __syncthreads();
  int node0 = b << BSH;
#pragma unroll
  for (int i = t; i < 512; i += 256) {
    int node = node0 + i;
    if (node < NNODES) rowptr[node] = beg + pos[i];
  }
  __syncthreads();
  for (int e = beg + t; e < end; e += 256) {
    int rec = ebuf[e];
    int c = ((unsigned)rec) >> 19;
    int lrank = atomicAdd(&pos[c], 1);
    int srcv = (rec >> 3) & 0xFFFF;
    int etv = rec & 7;
    edata[beg + lrank] = srcv * NOUT + etv * F;  // byte offset in fp8 xrs
  }
}

// ====== GEMM: xrs[50000][1152](fp8) = A[50000][128] @ Wt^T  (bf16 MFMA) =====
// 64-row block tile, A staged ONCE to LDS (16 KB, xor-swizzled, one barrier).
// Each of 4 waves sweeps col-tiles ct = iter*4+w (18 total of 64 cols),
// 64 MFMAs per ct. B read directly from global (shared by all 782 blocks ->
// L2-broadcast) with a depth-2 rolling prefetch (b0/b1/b2).
// K-chunk accumulation order c=0..3 unchanged -> bit-identical results.
// doCsr: blocks [0,196) instead run the coarse CSR scatter (hidden under GEMM).
__global__ __launch_bounds__(256, 3)
void gemm_xrs(const ushort* __restrict__ A, const ushort* __restrict__ Wt,
              unsigned char* __restrict__ xrs, int doCsr,
              const int* __restrict__ src, const int* __restrict__ dst,
              const int* __restrict__ et, int* __restrict__ bcur,
              int* __restrict__ ebuf) {
  __shared__ uint4 As[1024];  // 64 rows x 16 uint4, xor-swizzled
  __shared__ int lhist[NBKT];
  __shared__ int lbase[NBKT];
  const int tid = threadIdx.x;

  if (doCsr && blockIdx.x < CSR_BLOCKS) {
    // ---- coarse scatter: record = (dst_local<<19)|(src<<3)|et ----
    if (tid < NBKT) lhist[tid] = 0;
    __syncthreads();
    int e0 = blockIdx.x * 4096;
    int rec[16], cc[16], lr[16];
#pragma unroll
    for (int i = 0; i < 16; ++i) {
      int e = e0 + tid + i * 256;
      if (e < NEDGES) {
        int d = dst[e];
        cc[i] = d >> BSH;
        rec[i] = ((d & 511) << 19) | (src[e] << 3) | et[e];
        lr[i] = atomicAdd(&lhist[cc[i]], 1);
      } else {
        cc[i] = -1;
      }
    }
    __syncthreads();
    if (tid < NBKT && lhist[tid] > 0) lbase[tid] = atomicAdd(&bcur[tid], lhist[tid]);
    __syncthreads();
#pragma unroll
    for (int i = 0; i < 16; ++i)
      if (cc[i] >= 0) ebuf[lbase[cc[i]] + lr[i]] = rec[i];
    return;
  }

  const int tile = blockIdx.x - (doCsr ? CSR_BLOCKS : 0);
  const int row0 = tile * 64;
  const int lane = tid & 63;
  const int w = tid >> 6;
  const int i16 = lane & 15, q = lane >> 4;

  // Stage A-tile: 1024 uint4 slots, 4 per thread.
  uint4 va[4];
#pragma unroll
  for (int i = 0; i < 4; ++i) {
    int L = tid + i * 256;
    int r = L >> 4, c4 = L & 15;
    int agr = row0 + r; if (agr >= NNODES) agr = NNODES - 1;
    va[i] = *(const uint4*)(A + (size_t)agr * F + c4 * 8);
  }
#pragma unroll
  for (int i = 0; i < 4; ++i) {
    int L = tid + i * 256;
    int r = L >> 4, c4 = L & 15;
    As[r * 16 + (c4 ^ (r & 15))] = va[i];
  }
  __syncthreads();

  // B loader: step s -> col-tile ct=(s>>2)*4+w, k-chunk c=s&3.
  auto ldB = [&](bf16x8* d, int s) {
    int ct = (s >> 2) * 4 + w;
    int c = s & 3;
#pragma unroll
    for (int ni = 0; ni < 4; ++ni) {
      int r = ct * 64 + ni * 16 + i16;
      if (r > NOUT - 1) r = NOUT - 1;  // clamp (inactive waves only)
      d[ni] = *(const bf16x8*)(Wt + (size_t)r * F + c * 32 + q * 8);
    }
  };

  bf16x8 b0[4], b1[4], b2[4], af[4];
  ldB(b0, 0);
  ldB(b1, 1);

#pragma unroll
  for (int iter = 0; iter < 5; ++iter) {
    const int ct = iter * 4 + w;
    const bool active = ct < 18;
    f32x4 acc[4][4];
#pragma unroll
    for (int a = 0; a < 4; ++a)
#pragma unroll
      for (int b = 0; b < 4; ++b) acc[a][b] = (f32x4)0.f;

#pragma unroll
    for (int c = 0; c < 4; ++c) {
      int s = iter * 4 + c;
      if (s + 2 < 20) ldB(b2, s + 2);
      if (active) {
#pragma unroll
        for (int mi = 0; mi < 4; ++mi) {
          int r = mi * 16 + i16;
          af[mi] = *(const bf16x8*)&As[r * 16 + ((c * 4 + q) ^ (r & 15))];
        }
        // Swapped operands: D[m=weight feature][n=node row]
#pragma unroll
        for (int mi = 0; mi < 4; ++mi)
#pragma unroll
          for (int ni = 0; ni < 4; ++ni)
            acc[mi][ni] = __builtin_amdgcn_mfma_f32_16x16x32_bf16(
                b0[ni], af[mi], acc[mi][ni], 0, 0, 0);
      }
#pragma unroll
      for (int ni = 0; ni < 4; ++ni) { b0[ni] = b1[ni]; b1[ni] = b2[ni]; }
    }

    if (active) {
      // lane holds rows (node) = row0+mi*16+i16,
      // cols (feature) = ct*64 + ni*16 + q*4 + [0..3] -> 4 fp8 -> uint.
#pragma unroll
      for (int mi = 0; mi < 4; ++mi) {
        int row = row0 + mi * 16 + i16;
        bool ok = row < NNODES;
        size_t rb = (size_t)row * NOUT + ct * 64 + q * 4;
#pragma unroll
        for (int ni = 0; ni < 4; ++ni) {
          f32x4 v = acc[mi][ni];
          unsigned pk = 0;
          pk = __builtin_amdgcn_cvt_pk_fp8_f32(v[0], v[1], pk, false);
          pk = __builtin_amdgcn_cvt_pk_fp8_f32(v[2], v[3], pk, true);
          if (ok) *(unsigned*)(xrs + rb + ni * 16) = pk;
        }
      }
    }
  }
}

// ========== aggregate: h_next[dst] = relu(sum_e xrs[edata] + self + b) ======
__global__ __launch_bounds__(256)
void k_aggregate(const unsigned char* __restrict__ xrs,
                 const int* __restrict__ rowptr, const int* __restrict__ edata,
                 const float* __restrict__ bias, ushort* __restrict__ hout) {
  int node = (blockIdx.x * 256 + threadIdx.x) >> 6;
  int lane = threadIdx.x & 63;
  if (node >= NNODES) return;
  int beg = rowptr[node], end = rowptr[node + 1];

  unsigned sv = ((const ushort*)(xrs + (size_t)node * NOUT + NREL * F))[lane];
  f32x2 sf = __builtin_amdgcn_cvt_pk_f32_fp8(sv, false);
  float ax = sf[0], ay = sf[1];

  for (int base = beg; base < end; base += 64) {
    int cnt = end - base; if (cnt > 64) cnt = 64;
    int my = (base + lane < end) ? edata[base + lane] : 0;
    int e = 0;
    for (; e + 16 <= cnt; e += 16) {
      unsigned v[16];
#pragma unroll
      for (int k = 0; k < 16; ++k)
        v[k] = ((const ushort*)(xrs + (size_t)__builtin_amdgcn_readlane(my, e + k)))[lane];
#pragma unroll
      for (int k = 0; k < 16; ++k) {
        f32x2 f = __builtin_amdgcn_cvt_pk_f32_fp8(v[k], false);
        ax += f[0]; ay += f[1];
      }
    }
    for (; e + 4 <= cnt; e += 4) {
      unsigned v[4];
#pragma unroll
      for (int k = 0; k < 4; ++k)
        v[k] = ((const ushort*)(xrs + (size_t)__builtin_amdgcn_readlane(my, e + k)))[lane];
#pragma unroll
      for (int k = 0; k < 4; ++k) {
        f32x2 f = __builtin_amdgcn_cvt_pk_f32_fp8(v[k], false);
        ax += f[0]; ay += f[1];
      }
    }
    for (; e < cnt; ++e) {
      unsigned vv = ((const ushort*)(xrs + (size_t)__builtin_amdgcn_readlane(my, e)))[lane];
      f32x2 f = __builtin_amdgcn_cvt_pk_f32_fp8(vv, false);
      ax += f[0]; ay += f[1];
    }
  }

  float2 bb = ((const float2*)bias)[lane];
  ax = fmaxf(ax + bb.x, 0.f);
  ay = fmaxf(ay + bb.y, 0.f);
  ((unsigned*)(hout + (size_t)node * F))[lane] = f2bf(ax) | (f2bf(ay) << 16);
}

// ============ mean-pool + final fc fused (completion counter) ===============
__global__ __launch_bounds__(256)
void k_colsum_fc(const ushort* __restrict__ h2, float* __restrict__ pooled,
                 unsigned* __restrict__ counter, const float* __restrict__ fcw,
                 const float* __restrict__ fcb, float* __restrict__ out) {
  __shared__ float red[4][128];
  __shared__ unsigned lastFlag;
  const int j = threadIdx.x & 63;
  const int wv = threadIdx.x >> 6;
  float sx = 0.f, sy = 0.f;
  for (int r0 = blockIdx.x * 16 + wv * 4; r0 < NNODES; r0 += gridDim.x * 16) {
    const unsigned* p = (const unsigned*)h2 + (size_t)r0 * 64 + j;
    unsigned v0 = p[0];
    unsigned v1 = (r0 + 1 < NNODES) ? p[64] : 0;
    unsigned v2 = (r0 + 2 < NNODES) ? p[128] : 0;
    unsigned v3 = (r0 + 3 < NNODES) ? p[192] : 0;
    sx += bf2f(v0 & 0xffffu) + bf2f(v1 & 0xffffu) +
          bf2f(v2 & 0xffffu) + bf2f(v3 & 0xffffu);
    sy += bf2f(v0 >> 16) + bf2f(v1 >> 16) + bf2f(v2 >> 16) + bf2f(v3 >> 16);
  }
  red[wv][2 * j] = sx;
  red[wv][2 * j + 1] = sy;
  __syncthreads();
  if (threadIdx.x < 128) {
    float s = red[0][threadIdx.x] + red[1][threadIdx.x] +
              red[2][threadIdx.x] + red[3][threadIdx.x];
    atomicAdd(&pooled[threadIdx.x], s);
  }
  __syncthreads();
  if (threadIdx.x == 0) {
    __threadfence();
    lastFlag = (atomicAdd(counter, 1u) == (unsigned)gridDim.x - 1u) ? 1u : 0u;
  }
  __syncthreads();
  if (lastFlag) {
    __shared__ float sred[128];
    int t = threadIdx.x;
    if (t < 128)
      sred[t] = atomicAdd(&pooled[t], 0.0f) * (1.0f / (float)NNODES) * fcw[t];
    __syncthreads();
    if (t == 0) {
      float v = 0.f;
      for (int i = 0; i < 128; ++i) v += sred[i];
      v += fcb[0];
      out[0] = 1.f / (1.f + expf(-v));
    }
  }
}

// ============================================================================
extern "C" void kernel_launch(void* const* d_in, const int* in_sizes, int n_in,
                              void* d_out, int out_size, void* d_ws, size_t ws_size,
                              hipStream_t stream) {
  const float* in_feat = (const float*)d_in[0];
  const float* W1      = (const float*)d_in[1];
  const float* W1s     = (const float*)d_in[2];
  const float* b1      = (const float*)d_in[3];
  const float* W2      = (const float*)d_in[4];
  const float* W2s     = (const float*)d_in[5];
  const float* b2      = (const float*)d_in[6];
  const float* fcw     = (const float*)d_in[7];
  const float* fcb     = (const float*)d_in[8];
  const int*   src     = (const int*)d_in[9];
  const int*   dst     = (const int*)d_in[10];
  const int*   et      = (const int*)d_in[11];
  float* out = (float*)d_out;

  // Workspace (~110 MB)
  unsigned char* xrs = (unsigned char*)d_ws;              // [50000][1152] fp8
  ushort* feat0 = (ushort*)(xrs + (size_t)NNODES * NOUT); // [50000][128] bf16
  ushort* h1    = feat0 + (size_t)NNODES * F;             // [50000][128]
  ushort* h2    = h1 + (size_t)NNODES * F;                // [50000][128]
  ushort* Wt1   = h2 + (size_t)NNODES * F;                // [1152][128]
  ushort* Wt2   = Wt1 + (size_t)NOUT * F;                 // [1152][128]
  float*    pooled  = (float*)(Wt2 + (size_t)NOUT * F);   // [128]   } one
  unsigned* counter = (unsigned*)(pooled + 128);          // [1]     } memset
  int*      bcnt    = (int*)(counter + 1);                // [NBKT]  } region
  int*   rowptr = bcnt + NBKT;                            // [NNODES+1]
  int*   bbase  = rowptr + NNODES + 2;                    // [NBKT]
  int*   bcur   = bbase + NBKT;                           // [NBKT]
  int*   ebuf   = bcur + NBKT + 1;                        // [NEDGES]
  int*   edata  = ebuf + NEDGES;                          // [NEDGES]

  // single memset: pooled + counter + bcnt
  hipMemsetAsync(pooled, 0, (128 + 1 + NBKT) * sizeof(float), stream);

  // fused prep: coarse hist | feat cvt | weight prep x2
  k_prep<<<PREP_CHIST + PREP_CVT + 2 * PREP_W, 256, 0, stream>>>(
      dst, bcnt, in_feat, feat0, W1, W1s, Wt1, W2, W2s, Wt2);
  k_cscan<<<1, 128, 0, stream>>>(bcnt, bbase, bcur, rowptr);

  const int aggBlocks = (NNODES * 64 + 255) / 256;     // 12500

  // Layer 1 GEMM with CSR-scatter fused (scatter hidden under GEMM)
  gemm_xrs<<<CSR_BLOCKS + NT64, 256, 0, stream>>>(
      feat0, Wt1, xrs, 1, src, dst, et, bcur, ebuf);
  k_fsort<<<NBKT, 256, 0, stream>>>(ebuf, bbase, bcnt, rowptr, edata);
  k_aggregate<<<aggBlocks, 256, 0, stream>>>(xrs, rowptr, edata, b1, h1);
  // Layer 2
  gemm_xrs<<<NT64, 256, 0, stream>>>(
      h1, Wt2, xrs, 0, src, dst, et, bcur, ebuf);
  k_aggregate<<<aggBlocks, 256, 0, stream>>>(xrs, rowptr, edata, b2, h2);

  // Mean-pool + fc + sigmoid (fused, completion-counter)
  k_colsum_fc<<<784, 256, 0, stream>>>(h2, pooled, counter, fcw, fcb, out);
}

// Round 14
// 293.072 us; speedup vs baseline: 1.1911x; 1.1911x over previous
//
#include <hip/hip_runtime.h>

#define NNODES 50000
#define NEDGES 800000
#define F 128
#define NREL 8
#define NOUT 1152   // 9*128: 8 relations + self-loop
#define NBKT 98     // ceil(50000 / 512) coarse buckets
#define BSH 9       // 512 nodes per bucket
#define NTILES 391  // ceil(50000/128)
#define GEMM_BLOCKS (8 * 9 * 49)   // 3528 (XCD-swizzled)
#define CSR_BLOCKS 196

typedef short bf16x8 __attribute__((ext_vector_type(8)));
typedef float f32x4 __attribute__((ext_vector_type(4)));
typedef float f32x2 __attribute__((ext_vector_type(2)));

__device__ __forceinline__ unsigned f2bf(float f) {  // RNE
  unsigned u = __float_as_uint(f);
  u += 0x7fffu + ((u >> 16) & 1u);
  return u >> 16;
}
__device__ __forceinline__ float bf2f(unsigned v) {
  return __uint_as_float(v << 16);
}

// ========== fused prep: chist | cvt | prepw(W1) | prepw(W2) =================
#define PREP_CHIST 196
#define PREP_CVT   12500   // 50000*128/2 / 256
#define PREP_W     576     // 1152*128 / 256
__global__ __launch_bounds__(256)
void k_prep(const int* __restrict__ dst, int* __restrict__ bcnt,
            const float* __restrict__ in_feat, ushort* __restrict__ feat0,
            const float* __restrict__ W1, const float* __restrict__ W1s,
            ushort* __restrict__ Wt1,
            const float* __restrict__ W2, const float* __restrict__ W2s,
            ushort* __restrict__ Wt2) {
  const int b = blockIdx.x, t = threadIdx.x;
  if (b < PREP_CHIST) {
    __shared__ int hist[NBKT];
    if (t < NBKT) hist[t] = 0;
    __syncthreads();
    int e0 = b * 4096;
#pragma unroll
    for (int i = 0; i < 16; ++i) {
      int e = e0 + t + i * 256;
      if (e < NEDGES) atomicAdd(&hist[dst[e] >> BSH], 1);
    }
    __syncthreads();
    if (t < NBKT && hist[t] > 0) atomicAdd(&bcnt[t], hist[t]);
  } else if (b < PREP_CHIST + PREP_CVT) {
    int i = (b - PREP_CHIST) * 256 + t;  // exactly 3.2M
    float2 v = ((const float2*)in_feat)[i];
    ((unsigned*)feat0)[i] = f2bf(v.x) | (f2bf(v.y) << 16);
  } else {
    int w2 = (b >= PREP_CHIST + PREP_CVT + PREP_W);
    int idx = (b - PREP_CHIST - PREP_CVT - (w2 ? PREP_W : 0)) * 256 + t;
    int n = idx >> 7, k = idx & 127;
    int r = n >> 7, c = n & 127;
    const float* Wr = w2 ? W2 : W1;
    const float* Ws = w2 ? W2s : W1s;
    float v = (r < NREL) ? Wr[((size_t)r * F + k) * F + c] : Ws[(size_t)k * F + c];
    (w2 ? Wt2 : Wt1)[idx] = (ushort)f2bf(v);
  }
}

// ================= CSR scan =================================================
__global__ __launch_bounds__(128)
void k_cscan(const int* __restrict__ bcnt, int* __restrict__ bbase,
             int* __restrict__ bcur, int* __restrict__ rowptr) {
  __shared__ int s[128];
  int t = threadIdx.x;
  int v = (t < NBKT) ? bcnt[t] : 0;
  s[t] = v;
  __syncthreads();
  for (int off = 1; off < 128; off <<= 1) {
    int x = (t >= off) ? s[t - off] : 0;
    __syncthreads();
    s[t] += x;
    __syncthreads();
  }
  if (t < NBKT) { bbase[t] = s[t] - v; bcur[t] = s[t] - v; }
  if (t == 0) rowptr[NNODES] = NEDGES;
}

__global__ __launch_bounds__(256)
void k_fsort(const int* __restrict__ ebuf, const int* __restrict__ bbase,
             const int* __restrict__ bcnt, int* __restrict__ rowptr,
             int* __restrict__ edata) {
  __shared__ int cnt[512];
  __shared__ int pos[512];
  __shared__ int ws2[256];
  const int b = blockIdx.x, t = threadIdx.x;
  const int beg = bbase[b], end = beg + bcnt[b];
  cnt[t] = 0; cnt[t + 256] = 0;
  __syncthreads();
  for (int e = beg + t; e < end; e += 256)
    atomicAdd(&cnt[((unsigned)ebuf[e]) >> 19], 1);
  __syncthreads();
  int a = cnt[2 * t], b2 = cnt[2 * t + 1];
  ws2[t] = a + b2;
  __syncthreads();
  for (int off = 1; off < 256; off <<= 1) {
    int x = (t >= off) ? ws2[t - off] : 0;
    __syncthreads();
    ws2[t] += x;
    __syncthreads();
  }
  int ep = ws2[t] - (a + b2);
  pos[2 * t] = ep;
  pos[2 * t + 1] = ep + a;
  __syncthreads();
  int node0 = b << BSH;
#pragma unroll
  for (int i = t; i < 512; i += 256) {
    int node = node0 + i;
    if (node < NNODES) rowptr[node] = beg + pos[i];
  }
  __syncthreads();
  for (int e = beg + t; e < end; e += 256) {
    int rec = ebuf[e];
    int c = ((unsigned)rec) >> 19;
    int lrank = atomicAdd(&pos[c], 1);
    int srcv = (rec >> 3) & 0xFFFF;
    int etv = rec & 7;
    edata[beg + lrank] = srcv * NOUT + etv * F;  // byte offset in fp8 xrs
  }
}

// ====== GEMM: xrs[50000][1152](fp8) = A[50000][128] @ Wt^T  (bf16 MFMA) =====
// R12 structure (full-K, one barrier, XOR-swizzled 64KB LDS) but 512 threads:
// 8 waves, each 32x64 (2x4 frags, 8 MFMAs/chunk) -> 4 waves/SIMD for phase
// overlap. K-chunk order c=0..3 unchanged -> bit-identical results.
// doCsr: blocks [0,196) instead run the coarse CSR scatter.
__global__ __launch_bounds__(512, 4)
void gemm_xrs(const ushort* __restrict__ A, const ushort* __restrict__ Wt,
              unsigned char* __restrict__ xrs, int doCsr,
              const int* __restrict__ src, const int* __restrict__ dst,
              const int* __restrict__ et, int* __restrict__ bcur,
              int* __restrict__ ebuf) {
  __shared__ uint4 As[2048];  // 128 rows x 16 uint4, xor-swizzled
  __shared__ uint4 Bs[2048];
  __shared__ int lhist[NBKT];
  __shared__ int lbase[NBKT];
  const int tid = threadIdx.x;

  if (doCsr && blockIdx.x < CSR_BLOCKS) {
    // ---- coarse scatter: record = (dst_local<<19)|(src<<3)|et ----
    if (tid < NBKT) lhist[tid] = 0;
    __syncthreads();
    int e0 = blockIdx.x * 4096;
    int rec[8], cc[8], lr[8];
#pragma unroll
    for (int i = 0; i < 8; ++i) {
      int e = e0 + tid + i * 512;
      if (e < NEDGES) {
        int d = dst[e];
        cc[i] = d >> BSH;
        rec[i] = ((d & 511) << 19) | (src[e] << 3) | et[e];
        lr[i] = atomicAdd(&lhist[cc[i]], 1);
      } else {
        cc[i] = -1;
      }
    }
    __syncthreads();
    if (tid < NBKT && lhist[tid] > 0) lbase[tid] = atomicAdd(&bcur[tid], lhist[tid]);
    __syncthreads();
#pragma unroll
    for (int i = 0; i < 8; ++i)
      if (cc[i] >= 0) ebuf[lbase[cc[i]] + lr[i]] = rec[i];
    return;
  }

  const int id = blockIdx.x - (doCsr ? CSR_BLOCKS : 0);
  const int x = id & 7, j = id >> 3;
  const int tile = (j / 9) * 8 + x;
  const int cb = j % 9;
  if (tile >= NTILES) return;
  const int row0 = tile * 128;

  const int lane = tid & 63;
  const int w = tid >> 6;           // 0..7
  const int i16 = lane & 15, q = lane >> 4;
  const int mbase = (w & 3) * 32, nbase = (w >> 2) * 64;

  // Stage full tiles: 2048 uint4 slots each, 4 per thread.
  uint4 va[4], vb[4];
#pragma unroll
  for (int i = 0; i < 4; ++i) {
    int L = tid + i * 512;
    int r = L >> 4, c4 = L & 15;
    int agr = row0 + r; if (agr >= NNODES) agr = NNODES - 1;
    va[i] = *(const uint4*)(A + (size_t)agr * F + c4 * 8);
    vb[i] = *(const uint4*)(Wt + ((size_t)cb * 128 + r) * F + c4 * 8);
  }
#pragma unroll
  for (int i = 0; i < 4; ++i) {
    int L = tid + i * 512;
    int r = L >> 4, c4 = L & 15;
    int sidx = r * 16 + (c4 ^ (r & 15));
    As[sidx] = va[i];
    Bs[sidx] = vb[i];
  }
  __syncthreads();

  f32x4 acc[2][4];
#pragma unroll
  for (int a = 0; a < 2; ++a)
#pragma unroll
    for (int b = 0; b < 4; ++b) acc[a][b] = (f32x4)0.f;

#pragma unroll
  for (int c = 0; c < 4; ++c) {
    bf16x8 af[2], bfr[4];
#pragma unroll
    for (int mi = 0; mi < 2; ++mi) {
      int r = mbase + mi * 16 + i16;
      af[mi] = *(const bf16x8*)&As[r * 16 + ((c * 4 + q) ^ (r & 15))];
    }
#pragma unroll
    for (int ni = 0; ni < 4; ++ni) {
      int r = nbase + ni * 16 + i16;
      bfr[ni] = *(const bf16x8*)&Bs[r * 16 + ((c * 4 + q) ^ (r & 15))];
    }
    // Swapped operands: D[m=weight feature][n=node row]
#pragma unroll
    for (int mi = 0; mi < 2; ++mi)
#pragma unroll
      for (int ni = 0; ni < 4; ++ni)
        acc[mi][ni] = __builtin_amdgcn_mfma_f32_16x16x32_bf16(
            bfr[ni], af[mi], acc[mi][ni], 0, 0, 0);
  }

  // Epilogue: lane holds rows (node) = row0+mbase+mi*16+i16,
  // cols (feature) = cb*128 + nbase + ni*16 + q*4 + [0..3] -> 4 fp8 -> uint.
#pragma unroll
  for (int mi = 0; mi < 2; ++mi) {
    int row = row0 + mbase + mi * 16 + i16;
    bool ok = row < NNODES;
    size_t rb = (size_t)row * NOUT + cb * 128 + nbase + q * 4;
#pragma unroll
    for (int ni = 0; ni < 4; ++ni) {
      f32x4 v = acc[mi][ni];
      unsigned pk = 0;
      pk = __builtin_amdgcn_cvt_pk_fp8_f32(v[0], v[1], pk, false);
      pk = __builtin_amdgcn_cvt_pk_fp8_f32(v[2], v[3], pk, true);
      if (ok) *(unsigned*)(xrs + rb + ni * 16) = pk;
    }
  }
}

// ========== aggregate: h_next[dst] = relu(sum_e xrs[edata] + self + b) ======
__global__ __launch_bounds__(256)
void k_aggregate(const unsigned char* __restrict__ xrs,
                 const int* __restrict__ rowptr, const int* __restrict__ edata,
                 const float* __restrict__ bias, ushort* __restrict__ hout) {
  int node = (blockIdx.x * 256 + threadIdx.x) >> 6;
  int lane = threadIdx.x & 63;
  if (node >= NNODES) return;
  int beg = rowptr[node], end = rowptr[node + 1];

  unsigned sv = ((const ushort*)(xrs + (size_t)node * NOUT + NREL * F))[lane];
  f32x2 sf = __builtin_amdgcn_cvt_pk_f32_fp8(sv, false);
  float ax = sf[0], ay = sf[1];

  for (int base = beg; base < end; base += 64) {
    int cnt = end - base; if (cnt > 64) cnt = 64;
    int my = (base + lane < end) ? edata[base + lane] : 0;
    int e = 0;
    for (; e + 16 <= cnt; e += 16) {
      unsigned v[16];
#pragma unroll
      for (int k = 0; k < 16; ++k)
        v[k] = ((const ushort*)(xrs + (size_t)__builtin_amdgcn_readlane(my, e + k)))[lane];
#pragma unroll
      for (int k = 0; k < 16; ++k) {
        f32x2 f = __builtin_amdgcn_cvt_pk_f32_fp8(v[k], false);
        ax += f[0]; ay += f[1];
      }
    }
    for (; e + 4 <= cnt; e += 4) {
      unsigned v[4];
#pragma unroll
      for (int k = 0; k < 4; ++k)
        v[k] = ((const ushort*)(xrs + (size_t)__builtin_amdgcn_readlane(my, e + k)))[lane];
#pragma unroll
      for (int k = 0; k < 4; ++k) {
        f32x2 f = __builtin_amdgcn_cvt_pk_f32_fp8(v[k], false);
        ax += f[0]; ay += f[1];
      }
    }
    for (; e < cnt; ++e) {
      unsigned vv = ((const ushort*)(xrs + (size_t)__builtin_amdgcn_readlane(my, e)))[lane];
      f32x2 f = __builtin_amdgcn_cvt_pk_f32_fp8(vv, false);
      ax += f[0]; ay += f[1];
    }
  }

  float2 bb = ((const float2*)bias)[lane];
  ax = fmaxf(ax + bb.x, 0.f);
  ay = fmaxf(ay + bb.y, 0.f);
  ((unsigned*)(hout + (size_t)node * F))[lane] = f2bf(ax) | (f2bf(ay) << 16);
}

// ============ mean-pool + final fc fused (completion counter) ===============
__global__ __launch_bounds__(256)
void k_colsum_fc(const ushort* __restrict__ h2, float* __restrict__ pooled,
                 unsigned* __restrict__ counter, const float* __restrict__ fcw,
                 const float* __restrict__ fcb, float* __restrict__ out) {
  __shared__ float red[4][128];
  __shared__ unsigned lastFlag;
  const int j = threadIdx.x & 63;
  const int wv = threadIdx.x >> 6;
  float sx = 0.f, sy = 0.f;
  for (int r0 = blockIdx.x * 16 + wv * 4; r0 < NNODES; r0 += gridDim.x * 16) {
    const unsigned* p = (const unsigned*)h2 + (size_t)r0 * 64 + j;
    unsigned v0 = p[0];
    unsigned v1 = (r0 + 1 < NNODES) ? p[64] : 0;
    unsigned v2 = (r0 + 2 < NNODES) ? p[128] : 0;
    unsigned v3 = (r0 + 3 < NNODES) ? p[192] : 0;
    sx += bf2f(v0 & 0xffffu) + bf2f(v1 & 0xffffu) +
          bf2f(v2 & 0xffffu) + bf2f(v3 & 0xffffu);
    sy += bf2f(v0 >> 16) + bf2f(v1 >> 16) + bf2f(v2 >> 16) + bf2f(v3 >> 16);
  }
  red[wv][2 * j] = sx;
  red[wv][2 * j + 1] = sy;
  __syncthreads();
  if (threadIdx.x < 128) {
    float s = red[0][threadIdx.x] + red[1][threadIdx.x] +
              red[2][threadIdx.x] + red[3][threadIdx.x];
    atomicAdd(&pooled[threadIdx.x], s);
  }
  __syncthreads();
  if (threadIdx.x == 0) {
    __threadfence();
    lastFlag = (atomicAdd(counter, 1u) == (unsigned)gridDim.x - 1u) ? 1u : 0u;
  }
  __syncthreads();
  if (lastFlag) {
    __shared__ float sred[128];
    int t = threadIdx.x;
    if (t < 128)
      sred[t] = atomicAdd(&pooled[t], 0.0f) * (1.0f / (float)NNODES) * fcw[t];
    __syncthreads();
    if (t == 0) {
      float v = 0.f;
      for (int i = 0; i < 128; ++i) v += sred[i];
      v += fcb[0];
      out[0] = 1.f / (1.f + expf(-v));
    }
  }
}

// ============================================================================
extern "C" void kernel_launch(void* const* d_in, const int* in_sizes, int n_in,
                              void* d_out, int out_size, void* d_ws, size_t ws_size,
                              hipStream_t stream) {
  const float* in_feat = (const float*)d_in[0];
  const float* W1      = (const float*)d_in[1];
  const float* W1s     = (const float*)d_in[2];
  const float* b1      = (const float*)d_in[3];
  const float* W2      = (const float*)d_in[4];
  const float* W2s     = (const float*)d_in[5];
  const float* b2      = (const float*)d_in[6];
  const float* fcw     = (const float*)d_in[7];
  const float* fcb     = (const float*)d_in[8];
  const int*   src     = (const int*)d_in[9];
  const int*   dst     = (const int*)d_in[10];
  const int*   et      = (const int*)d_in[11];
  float* out = (float*)d_out;

  // Workspace (~110 MB)
  unsigned char* xrs = (unsigned char*)d_ws;              // [50000][1152] fp8
  ushort* feat0 = (ushort*)(xrs + (size_t)NNODES * NOUT); // [50000][128] bf16
  ushort* h1    = feat0 + (size_t)NNODES * F;             // [50000][128]
  ushort* h2    = h1 + (size_t)NNODES * F;                // [50000][128]
  ushort* Wt1   = h2 + (size_t)NNODES * F;                // [1152][128]
  ushort* Wt2   = Wt1 + (size_t)NOUT * F;                 // [1152][128]
  float*    pooled  = (float*)(Wt2 + (size_t)NOUT * F);   // [128]   } one
  unsigned* counter = (unsigned*)(pooled + 128);          // [1]     } memset
  int*      bcnt    = (int*)(counter + 1);                // [NBKT]  } region
  int*   rowptr = bcnt + NBKT;                            // [NNODES+1]
  int*   bbase  = rowptr + NNODES + 2;                    // [NBKT]
  int*   bcur   = bbase + NBKT;                           // [NBKT]
  int*   ebuf   = bcur + NBKT + 1;                        // [NEDGES]
  int*   edata  = ebuf + NEDGES;                          // [NEDGES]

  // single memset: pooled + counter + bcnt
  hipMemsetAsync(pooled, 0, (128 + 1 + NBKT) * sizeof(float), stream);

  // fused prep: coarse hist | feat cvt | weight prep x2
  k_prep<<<PREP_CHIST + PREP_CVT + 2 * PREP_W, 256, 0, stream>>>(
      dst, bcnt, in_feat, feat0, W1, W1s, Wt1, W2, W2s, Wt2);
  k_cscan<<<1, 128, 0, stream>>>(bcnt, bbase, bcur, rowptr);

  const int aggBlocks = (NNODES * 64 + 255) / 256;     // 12500

  // Layer 1 GEMM with CSR-scatter fused (scatter hidden under GEMM)
  gemm_xrs<<<CSR_BLOCKS + GEMM_BLOCKS, 512, 0, stream>>>(
      feat0, Wt1, xrs, 1, src, dst, et, bcur, ebuf);
  k_fsort<<<NBKT, 256, 0, stream>>>(ebuf, bbase, bcnt, rowptr, edata);
  k_aggregate<<<aggBlocks, 256, 0, stream>>>(xrs, rowptr, edata, b1, h1);
  // Layer 2
  gemm_xrs<<<GEMM_BLOCKS, 512, 0, stream>>>(
      h1, Wt2, xrs, 0, src, dst, et, bcur, ebuf);
  k_aggregate<<<aggBlocks, 256, 0, stream>>>(xrs, rowptr, edata, b2, h2);

  // Mean-pool + fc + sigmoid (fused, completion-counter)
  k_colsum_fc<<<784, 256, 0, stream>>>(h2, pooled, counter, fcw, fcb, out);
}

// Round 15
// 271.955 us; speedup vs baseline: 1.2836x; 1.0777x over previous
//
#include <hip/hip_runtime.h>

#define NNODES 50000
#define NEDGES 800000
#define F 128
#define NREL 8
#define NOUT 1152   // 9*128: 8 relations + self-loop
#define NBKT 98     // ceil(50000 / 512) coarse buckets
#define BSH 9       // 512 nodes per bucket
#define NTILES 391  // ceil(50000/128)
#define GEMM_BLOCKS (8 * 9 * 49)   // 3528 (XCD-swizzled)
#define CSR_BLOCKS 196

typedef short bf16x8 __attribute__((ext_vector_type(8)));
typedef float f32x4 __attribute__((ext_vector_type(4)));
typedef float f32x2 __attribute__((ext_vector_type(2)));

__device__ __forceinline__ unsigned f2bf(float f) {  // RNE
  unsigned u = __float_as_uint(f);
  u += 0x7fffu + ((u >> 16) & 1u);
  return u >> 16;
}
__device__ __forceinline__ float bf2f(unsigned v) {
  return __uint_as_float(v << 16);
}

// ========== fused prep: chist | cvt | prepw(W1) | prepw(W2) =================
#define PREP_CHIST 196
#define PREP_CVT   12500   // 50000*128/2 / 256
#define PREP_W     576     // 1152*128 / 256
__global__ __launch_bounds__(256)
void k_prep(const int* __restrict__ dst, int* __restrict__ bcnt,
            const float* __restrict__ in_feat, ushort* __restrict__ feat0,
            const float* __restrict__ W1, const float* __restrict__ W1s,
            ushort* __restrict__ Wt1,
            const float* __restrict__ W2, const float* __restrict__ W2s,
            ushort* __restrict__ Wt2) {
  const int b = blockIdx.x, t = threadIdx.x;
  if (b < PREP_CHIST) {
    __shared__ int hist[NBKT];
    if (t < NBKT) hist[t] = 0;
    __syncthreads();
    int e0 = b * 4096;
#pragma unroll
    for (int i = 0; i < 16; ++i) {
      int e = e0 + t + i * 256;
      if (e < NEDGES) atomicAdd(&hist[dst[e] >> BSH], 1);
    }
    __syncthreads();
    if (t < NBKT && hist[t] > 0) atomicAdd(&bcnt[t], hist[t]);
  } else if (b < PREP_CHIST + PREP_CVT) {
    int i = (b - PREP_CHIST) * 256 + t;  // exactly 3.2M
    float2 v = ((const float2*)in_feat)[i];
    ((unsigned*)feat0)[i] = f2bf(v.x) | (f2bf(v.y) << 16);
  } else {
    int w2 = (b >= PREP_CHIST + PREP_CVT + PREP_W);
    int idx = (b - PREP_CHIST - PREP_CVT - (w2 ? PREP_W : 0)) * 256 + t;
    int n = idx >> 7, k = idx & 127;
    int r = n >> 7, c = n & 127;
    const float* Wr = w2 ? W2 : W1;
    const float* Ws = w2 ? W2s : W1s;
    float v = (r < NREL) ? Wr[((size_t)r * F + k) * F + c] : Ws[(size_t)k * F + c];
    (w2 ? Wt2 : Wt1)[idx] = (ushort)f2bf(v);
  }
}

// ================= CSR scan =================================================
__global__ __launch_bounds__(128)
void k_cscan(const int* __restrict__ bcnt, int* __restrict__ bbase,
             int* __restrict__ bcur, int* __restrict__ rowptr) {
  __shared__ int s[128];
  int t = threadIdx.x;
  int v = (t < NBKT) ? bcnt[t] : 0;
  s[t] = v;
  __syncthreads();
  for (int off = 1; off < 128; off <<= 1) {
    int x = (t >= off) ? s[t - off] : 0;
    __syncthreads();
    s[t] += x;
    __syncthreads();
  }
  if (t < NBKT) { bbase[t] = s[t] - v; bcur[t] = s[t] - v; }
  if (t == 0) rowptr[NNODES] = NEDGES;
}

__global__ __launch_bounds__(256)
void k_fsort(const int* __restrict__ ebuf, const int* __restrict__ bbase,
             const int* __restrict__ bcnt, int* __restrict__ rowptr,
             int* __restrict__ edata) {
  __shared__ int cnt[512];
  __shared__ int pos[512];
  __shared__ int ws2[256];
  const int b = blockIdx.x, t = threadIdx.x;
  const int beg = bbase[b], end = beg + bcnt[b];
  cnt[t] = 0; cnt[t + 256] = 0;
  __syncthreads();
  for (int e = beg + t; e < end; e += 256)
    atomicAdd(&cnt[((unsigned)ebuf[e]) >> 19], 1);
  __syncthreads();
  int a = cnt[2 * t], b2 = cnt[2 * t + 1];
  ws2[t] = a + b2;
  __syncthreads();
  for (int off = 1; off < 256; off <<= 1) {
    int x = (t >= off) ? ws2[t - off] : 0;
    __syncthreads();
    ws2[t] += x;
    __syncthreads();
  }
  int ep = ws2[t] - (a + b2);
  pos[2 * t] = ep;
  pos[2 * t + 1] = ep + a;
  __syncthreads();
  int node0 = b << BSH;
#pragma unroll
  for (int i = t; i < 512; i += 256) {
    int node = node0 + i;
    if (node < NNODES) rowptr[node] = beg + pos[i];
  }
  __syncthreads();
  for (int e = beg + t; e < end; e += 256) {
    int rec = ebuf[e];
    int c = ((unsigned)rec) >> 19;
    int lrank = atomicAdd(&pos[c], 1);
    int srcv = (rec >> 3) & 0xFFFF;
    int etv = rec & 7;
    edata[beg + lrank] = srcv * NOUT + etv * F;  // byte offset in fp8 xrs
  }
}

// ====== GEMM: xrs[50000][1152](fp8) = A[50000][128] @ Wt^T  (bf16 MFMA) =====
// R14 structure (proven): full-K, one barrier, XOR-swizzled 64KB LDS,
// 512 threads / 8 waves (32x64 each). Bit-identical results.
// doCsr: blocks [0,196) instead run the coarse CSR scatter.
__global__ __launch_bounds__(512, 4)
void gemm_xrs(const ushort* __restrict__ A, const ushort* __restrict__ Wt,
              unsigned char* __restrict__ xrs, int doCsr,
              const int* __restrict__ src, const int* __restrict__ dst,
              const int* __restrict__ et, int* __restrict__ bcur,
              int* __restrict__ ebuf) {
  __shared__ uint4 As[2048];  // 128 rows x 16 uint4, xor-swizzled
  __shared__ uint4 Bs[2048];
  __shared__ int lhist[NBKT];
  __shared__ int lbase[NBKT];
  const int tid = threadIdx.x;

  if (doCsr && blockIdx.x < CSR_BLOCKS) {
    // ---- coarse scatter: record = (dst_local<<19)|(src<<3)|et ----
    if (tid < NBKT) lhist[tid] = 0;
    __syncthreads();
    int e0 = blockIdx.x * 4096;
    int rec[8], cc[8], lr[8];
#pragma unroll
    for (int i = 0; i < 8; ++i) {
      int e = e0 + tid + i * 512;
      if (e < NEDGES) {
        int d = dst[e];
        cc[i] = d >> BSH;
        rec[i] = ((d & 511) << 19) | (src[e] << 3) | et[e];
        lr[i] = atomicAdd(&lhist[cc[i]], 1);
      } else {
        cc[i] = -1;
      }
    }
    __syncthreads();
    if (tid < NBKT && lhist[tid] > 0) lbase[tid] = atomicAdd(&bcur[tid], lhist[tid]);
    __syncthreads();
#pragma unroll
    for (int i = 0; i < 8; ++i)
      if (cc[i] >= 0) ebuf[lbase[cc[i]] + lr[i]] = rec[i];
    return;
  }

  const int id = blockIdx.x - (doCsr ? CSR_BLOCKS : 0);
  const int x = id & 7, j = id >> 3;
  const int tile = (j / 9) * 8 + x;
  const int cb = j % 9;
  if (tile >= NTILES) return;
  const int row0 = tile * 128;

  const int lane = tid & 63;
  const int w = tid >> 6;           // 0..7
  const int i16 = lane & 15, q = lane >> 4;
  const int mbase = (w & 3) * 32, nbase = (w >> 2) * 64;

  // Stage full tiles: 2048 uint4 slots each, 4 per thread.
  uint4 va[4], vb[4];
#pragma unroll
  for (int i = 0; i < 4; ++i) {
    int L = tid + i * 512;
    int r = L >> 4, c4 = L & 15;
    int agr = row0 + r; if (agr >= NNODES) agr = NNODES - 1;
    va[i] = *(const uint4*)(A + (size_t)agr * F + c4 * 8);
    vb[i] = *(const uint4*)(Wt + ((size_t)cb * 128 + r) * F + c4 * 8);
  }
#pragma unroll
  for (int i = 0; i < 4; ++i) {
    int L = tid + i * 512;
    int r = L >> 4, c4 = L & 15;
    int sidx = r * 16 + (c4 ^ (r & 15));
    As[sidx] = va[i];
    Bs[sidx] = vb[i];
  }
  __syncthreads();

  f32x4 acc[2][4];
#pragma unroll
  for (int a = 0; a < 2; ++a)
#pragma unroll
    for (int b = 0; b < 4; ++b) acc[a][b] = (f32x4)0.f;

#pragma unroll
  for (int c = 0; c < 4; ++c) {
    bf16x8 af[2], bfr[4];
#pragma unroll
    for (int mi = 0; mi < 2; ++mi) {
      int r = mbase + mi * 16 + i16;
      af[mi] = *(const bf16x8*)&As[r * 16 + ((c * 4 + q) ^ (r & 15))];
    }
#pragma unroll
    for (int ni = 0; ni < 4; ++ni) {
      int r = nbase + ni * 16 + i16;
      bfr[ni] = *(const bf16x8*)&Bs[r * 16 + ((c * 4 + q) ^ (r & 15))];
    }
    // Swapped operands: D[m=weight feature][n=node row]
#pragma unroll
    for (int mi = 0; mi < 2; ++mi)
#pragma unroll
      for (int ni = 0; ni < 4; ++ni)
        acc[mi][ni] = __builtin_amdgcn_mfma_f32_16x16x32_bf16(
            bfr[ni], af[mi], acc[mi][ni], 0, 0, 0);
  }

  // Epilogue: lane holds rows (node) = row0+mbase+mi*16+i16,
  // cols (feature) = cb*128 + nbase + ni*16 + q*4 + [0..3] -> 4 fp8 -> uint.
#pragma unroll
  for (int mi = 0; mi < 2; ++mi) {
    int row = row0 + mbase + mi * 16 + i16;
    bool ok = row < NNODES;
    size_t rb = (size_t)row * NOUT + cb * 128 + nbase + q * 4;
#pragma unroll
    for (int ni = 0; ni < 4; ++ni) {
      f32x4 v = acc[mi][ni];
      unsigned pk = 0;
      pk = __builtin_amdgcn_cvt_pk_fp8_f32(v[0], v[1], pk, false);
      pk = __builtin_amdgcn_cvt_pk_fp8_f32(v[2], v[3], pk, true);
      if (ok) *(unsigned*)(xrs + rb + ni * 16) = pk;
    }
  }
}

// ========== aggregate: h_next[dst] = relu(sum_e xrs[edata] + self + b) ======
// Paired-edge: half-wave (32 lanes) per edge, 4B dword loads (full 128B row
// per half-wave), 8 pairs (16 edges) in flight, __shfl for offsets,
// __shfl_xor(32) merges halves. 12500 blocks x 4 nodes = 50000 exactly.
// hout != null: store bf16 h. pooled_p != null: LDS-reduce block's 4 nodes,
// atomicAdd into 64-slot-spread partials (pooling fused; h2 never written).
__global__ __launch_bounds__(256)
void k_aggregate(const unsigned char* __restrict__ xrs,
                 const int* __restrict__ rowptr, const int* __restrict__ edata,
                 const float* __restrict__ bias, ushort* __restrict__ hout,
                 float* __restrict__ pooled_p) {
  __shared__ float red[4][128];
  const int wv = threadIdx.x >> 6;
  const int node = blockIdx.x * 4 + wv;
  const int lane = threadIdx.x & 63;
  const int half = lane >> 5, sl = lane & 31;
  const int beg = rowptr[node], end = rowptr[node + 1];

  float a0 = 0.f, a1 = 0.f, a2 = 0.f, a3 = 0.f;
  // self-loop row (r=8), counted once by half 0
  if (half == 0) {
    unsigned sv = *(const unsigned*)(xrs + (size_t)node * NOUT + NREL * F + sl * 4);
    f32x2 lo = __builtin_amdgcn_cvt_pk_f32_fp8(sv, false);
    f32x2 hi = __builtin_amdgcn_cvt_pk_f32_fp8(sv, true);
    a0 += lo[0]; a1 += lo[1]; a2 += hi[0]; a3 += hi[1];
  }

  for (int base = beg; base < end; base += 64) {
    int cnt = end - base; if (cnt > 64) cnt = 64;
    int my = (base + lane < end) ? edata[base + lane] : 0;
    int pairs = cnt >> 1;
    int p = 0;
    for (; p + 8 <= pairs; p += 8) {
      unsigned v[8];
#pragma unroll
      for (int k = 0; k < 8; ++k) {
        int off = __shfl(my, 2 * (p + k) + half, 64);
        v[k] = *(const unsigned*)(xrs + (size_t)off + sl * 4);
      }
#pragma unroll
      for (int k = 0; k < 8; ++k) {
        f32x2 lo = __builtin_amdgcn_cvt_pk_f32_fp8(v[k], false);
        f32x2 hi = __builtin_amdgcn_cvt_pk_f32_fp8(v[k], true);
        a0 += lo[0]; a1 += lo[1]; a2 += hi[0]; a3 += hi[1];
      }
    }
    for (; p < pairs; ++p) {
      int off = __shfl(my, 2 * p + half, 64);
      unsigned vv = *(const unsigned*)(xrs + (size_t)off + sl * 4);
      f32x2 lo = __builtin_amdgcn_cvt_pk_f32_fp8(vv, false);
      f32x2 hi = __builtin_amdgcn_cvt_pk_f32_fp8(vv, true);
      a0 += lo[0]; a1 += lo[1]; a2 += hi[0]; a3 += hi[1];
    }
    if (cnt & 1) {
      int off = __shfl(my, cnt - 1, 64);
      if (half == 0) {
        unsigned vv = *(const unsigned*)(xrs + (size_t)off + sl * 4);
        f32x2 lo = __builtin_amdgcn_cvt_pk_f32_fp8(vv, false);
        f32x2 hi = __builtin_amdgcn_cvt_pk_f32_fp8(vv, true);
        a0 += lo[0]; a1 += lo[1]; a2 += hi[0]; a3 += hi[1];
      }
    }
  }

  // merge the two half-wave partial sums
  a0 += __shfl_xor(a0, 32, 64);
  a1 += __shfl_xor(a1, 32, 64);
  a2 += __shfl_xor(a2, 32, 64);
  a3 += __shfl_xor(a3, 32, 64);

  float4 bb = ((const float4*)bias)[sl];
  a0 = fmaxf(a0 + bb.x, 0.f);
  a1 = fmaxf(a1 + bb.y, 0.f);
  a2 = fmaxf(a2 + bb.z, 0.f);
  a3 = fmaxf(a3 + bb.w, 0.f);

  if (hout) {
    if (half == 0) {
      uint2 pk;
      pk.x = f2bf(a0) | (f2bf(a1) << 16);
      pk.y = f2bf(a2) | (f2bf(a3) << 16);
      ((uint2*)(hout + (size_t)node * F))[sl] = pk;
    }
  } else {
    if (half == 0) {
      red[wv][sl * 4 + 0] = a0;
      red[wv][sl * 4 + 1] = a1;
      red[wv][sl * 4 + 2] = a2;
      red[wv][sl * 4 + 3] = a3;
    }
    __syncthreads();
    if (threadIdx.x < 128) {
      float s = red[0][threadIdx.x] + red[1][threadIdx.x] +
                red[2][threadIdx.x] + red[3][threadIdx.x];
      atomicAdd(&pooled_p[(blockIdx.x & 63) * 128 + threadIdx.x], s);
    }
  }
}

// ================== final: reduce 64x128 partials + fc + sigmoid ============
__global__ __launch_bounds__(128)
void k_final(const float* __restrict__ pooled_p, const float* __restrict__ fcw,
             const float* __restrict__ fcb, float* __restrict__ out) {
  __shared__ float s[128];
  int t = threadIdx.x;
  float acc = 0.f;
#pragma unroll 8
  for (int k = 0; k < 64; ++k) acc += pooled_p[k * 128 + t];
  s[t] = acc * (1.0f / (float)NNODES) * fcw[t];
  __syncthreads();
  if (t == 0) {
    float v = 0.f;
    for (int i = 0; i < 128; ++i) v += s[i];
    v += fcb[0];
    out[0] = 1.f / (1.f + expf(-v));
  }
}

// ============================================================================
extern "C" void kernel_launch(void* const* d_in, const int* in_sizes, int n_in,
                              void* d_out, int out_size, void* d_ws, size_t ws_size,
                              hipStream_t stream) {
  const float* in_feat = (const float*)d_in[0];
  const float* W1      = (const float*)d_in[1];
  const float* W1s     = (const float*)d_in[2];
  const float* b1      = (const float*)d_in[3];
  const float* W2      = (const float*)d_in[4];
  const float* W2s     = (const float*)d_in[5];
  const float* b2      = (const float*)d_in[6];
  const float* fcw     = (const float*)d_in[7];
  const float* fcb     = (const float*)d_in[8];
  const int*   src     = (const int*)d_in[9];
  const int*   dst     = (const int*)d_in[10];
  const int*   et      = (const int*)d_in[11];
  float* out = (float*)d_out;

  // Workspace (~100 MB)
  unsigned char* xrs = (unsigned char*)d_ws;              // [50000][1152] fp8
  ushort* feat0 = (ushort*)(xrs + (size_t)NNODES * NOUT); // [50000][128] bf16
  ushort* h1    = feat0 + (size_t)NNODES * F;             // [50000][128]
  ushort* Wt1   = h1 + (size_t)NNODES * F;                // [1152][128]
  ushort* Wt2   = Wt1 + (size_t)NOUT * F;                 // [1152][128]
  float* pooled_p = (float*)(Wt2 + (size_t)NOUT * F);     // [64][128] } one
  int*   bcnt   = (int*)(pooled_p + 64 * 128);            // [NBKT]    } memset
  int*   rowptr = bcnt + NBKT;                            // [NNODES+1]
  int*   bbase  = rowptr + NNODES + 2;                    // [NBKT]
  int*   bcur   = bbase + NBKT;                           // [NBKT]
  int*   ebuf   = bcur + NBKT + 1;                        // [NEDGES]
  int*   edata  = ebuf + NEDGES;                          // [NEDGES]

  // single memset: pooled_p + bcnt
  hipMemsetAsync(pooled_p, 0, (64 * 128 + NBKT) * sizeof(float), stream);

  // fused prep: coarse hist | feat cvt | weight prep x2
  k_prep<<<PREP_CHIST + PREP_CVT + 2 * PREP_W, 256, 0, stream>>>(
      dst, bcnt, in_feat, feat0, W1, W1s, Wt1, W2, W2s, Wt2);
  k_cscan<<<1, 128, 0, stream>>>(bcnt, bbase, bcur, rowptr);

  const int aggBlocks = NNODES / 4;                    // 12500

  // Layer 1 GEMM with CSR-scatter fused (scatter hidden under GEMM)
  gemm_xrs<<<CSR_BLOCKS + GEMM_BLOCKS, 512, 0, stream>>>(
      feat0, Wt1, xrs, 1, src, dst, et, bcur, ebuf);
  k_fsort<<<NBKT, 256, 0, stream>>>(ebuf, bbase, bcnt, rowptr, edata);
  k_aggregate<<<aggBlocks, 256, 0, stream>>>(xrs, rowptr, edata, b1, h1, nullptr);
  // Layer 2 (pooling fused into aggregate; h2 never materialized)
  gemm_xrs<<<GEMM_BLOCKS, 512, 0, stream>>>(
      h1, Wt2, xrs, 0, src, dst, et, bcur, ebuf);
  k_aggregate<<<aggBlocks, 256, 0, stream>>>(xrs, rowptr, edata, b2, nullptr, pooled_p);

  // Reduce partials + fc + sigmoid
  k_final<<<1, 128, 0, stream>>>(pooled_p, fcw, fcb, out);
}